// Round 14
// baseline (16711.012 us; speedup 1.0000x reference)
//
#include <hip/hip_runtime.h>
#include <hip/hip_bf16.h>

typedef _Float16 f16x8 __attribute__((ext_vector_type(8)));
typedef float f32x4 __attribute__((ext_vector_type(4)));
typedef unsigned long long u64;

#define B_   128
#define T_   1024
#define H_   512
#define P_   32      // blocks per clique (16 h-cols each)
#define HC_  16
#define MB_  32      // batch rows per clique
#define NC_  8       // cliques: 0-3 layer1, 4-7 layer2
#define NWK_ 4       // worker waves (K-split); wave 4 = heater
#define SPIN_BOUND (1 << 20)   // worker spins bounded: wedge -> visible failure
#define HEAT_BOUND (1 << 14)   // heater spins bounded: never the hang source

// ws layout (bytes)
#define WS_HEXHI  0ull            // f16 [2][NC][MB][H] = 524288
#define WS_HEXLO  524288ull       // f16 [2][NC][MB][H] = 524288
#define WS_FLAGR  1048576ull      // u32 [NC][32][32] 128B-padded flags = 32768
#define WS_FLAGX  1081344ull      // u32 [4][32][32]  128B-padded       = 16384
#define WS_XCC    1097728ull      // u32 [256] = 1024
#define WS_MECH   1098752ull      // u32 [256] = 1024
#define WS_PROBE  1099776ull      // u32 [NC][32] 128B-padded = 1024
#define WS_ZEROL  1100800ull
#define WS_HLAST  1100800ull      // f32 [B][H] = 262144
#define WS_H1HI   1362944ull      // f16 [B][T][H] = 134217728
#define WS_H1LO   135580672ull
#define WS_NEED_SMALL 135580672ull
#define WS_NEED_FULL  269798400ull

#define MFMA(a, b, c) __builtin_amdgcn_mfma_f32_16x16x32_f16((a), (b), (c), 0, 0, 0)

// 16 pipelined dwordx4 loads from 4 bases (+0/64/128/192B), ONE vmcnt(0).
#define LD16(FLAGS, D, DB, P0, P1, P2, P3)                                      \
    asm volatile(                                                               \
        "global_load_dwordx4 %0, %16, off " FLAGS "\n\t"                        \
        "global_load_dwordx4 %1, %16, off offset:64 " FLAGS "\n\t"              \
        "global_load_dwordx4 %2, %16, off offset:128 " FLAGS "\n\t"             \
        "global_load_dwordx4 %3, %16, off offset:192 " FLAGS "\n\t"             \
        "global_load_dwordx4 %4, %17, off " FLAGS "\n\t"                        \
        "global_load_dwordx4 %5, %17, off offset:64 " FLAGS "\n\t"              \
        "global_load_dwordx4 %6, %17, off offset:128 " FLAGS "\n\t"             \
        "global_load_dwordx4 %7, %17, off offset:192 " FLAGS "\n\t"             \
        "global_load_dwordx4 %8, %18, off " FLAGS "\n\t"                        \
        "global_load_dwordx4 %9, %18, off offset:64 " FLAGS "\n\t"              \
        "global_load_dwordx4 %10, %18, off offset:128 " FLAGS "\n\t"            \
        "global_load_dwordx4 %11, %18, off offset:192 " FLAGS "\n\t"            \
        "global_load_dwordx4 %12, %19, off " FLAGS "\n\t"                       \
        "global_load_dwordx4 %13, %19, off offset:64 " FLAGS "\n\t"             \
        "global_load_dwordx4 %14, %19, off offset:128 " FLAGS "\n\t"            \
        "global_load_dwordx4 %15, %19, off offset:192 " FLAGS "\n\t"            \
        "s_waitcnt vmcnt(0)"                                                    \
        : "=&v"(D[0][0]), "=&v"(D[1][0]), "=&v"(D[2][0]), "=&v"(D[3][0]),       \
          "=&v"(D[0][1]), "=&v"(D[1][1]), "=&v"(D[2][1]), "=&v"(D[3][1]),       \
          "=&v"(DB[0][0]), "=&v"(DB[1][0]), "=&v"(DB[2][0]), "=&v"(DB[3][0]),   \
          "=&v"(DB[0][1]), "=&v"(DB[1][1]), "=&v"(DB[2][1]), "=&v"(DB[3][1])    \
        : "v"(P0), "v"(P1), "v"(P2), "v"(P3)                                    \
        : "memory")

// ---- agent-scope relaxed atomics (flags / h1 stores) ----
__device__ __forceinline__ unsigned ald4(const unsigned* p) {
    return __hip_atomic_load(p, __ATOMIC_RELAXED, __HIP_MEMORY_SCOPE_AGENT);
}
__device__ __forceinline__ void ast4(void* p, unsigned v) {
    __hip_atomic_store((unsigned*)p, v, __ATOMIC_RELAXED, __HIP_MEMORY_SCOPE_AGENT);
}
// ---- fast-path flag primitives (runtime-proven by the mechanism probe) ----
__device__ __forceinline__ void st4_plain(unsigned* p, unsigned v) {
    asm volatile("global_store_dword %0, %1, off" :: "v"(p), "v"(v) : "memory");
}
__device__ __forceinline__ unsigned ld4_sc1(const unsigned* p) {
    unsigned r;
    asm volatile("global_load_dword %0, %1, off sc1\n\ts_waitcnt vmcnt(0)"
                 : "=v"(r) : "v"(p) : "memory");
    return r;
}
__device__ __forceinline__ unsigned short f16bits(_Float16 h) {
    union { _Float16 f; unsigned short s; } u; u.f = h; return u.s;
}
// poll-side mini heat (r10: duty irrelevant; keeps exit granularity low)
__device__ __forceinline__ void heat(unsigned v) {
    float a = (float)(v & 7u) + 1.0f;
    #pragma unroll
    for (int i = 0; i < 16; ++i)
        asm volatile("v_fmac_f32 %0, %1, %2" : "+v"(a) : "v"(1.000001f), "v"(a));
    asm volatile("" :: "v"(a));
}
// HEATER WAVE spin: burn issue-dense FMAs until LDS epoch reaches target.
// Theory under test: DPM downclocks the ~idle-looking chip ~4x (all waves
// parked in s_waitcnt); a continuously-issuing wave per CU holds the boost.
__device__ __forceinline__ void heater_spin(volatile int* ep, int target) {
    float a0 = 1.0f, a1 = 1.25f, a2 = 1.5f, a3 = 1.75f;
    int it = 0;
    while (*ep < target) {
        #pragma unroll
        for (int i = 0; i < 16; ++i) {
            asm volatile("v_fmac_f32 %0, %1, %2" : "+v"(a0) : "v"(1.000001f), "v"(a0));
            asm volatile("v_fmac_f32 %0, %1, %2" : "+v"(a1) : "v"(1.000001f), "v"(a1));
            asm volatile("v_fmac_f32 %0, %1, %2" : "+v"(a2) : "v"(1.000001f), "v"(a2));
            asm volatile("v_fmac_f32 %0, %1, %2" : "+v"(a3) : "v"(1.000001f), "v"(a3));
        }
        if (++it > HEAT_BOUND) break;   // never the hang source
    }
    asm volatile("" :: "v"(a0), "v"(a1), "v"(a2), "v"(a3));
}
// gbuf index swizzle: spreads the 4-way reduce bank aliasing to 2-way (free).
__device__ __forceinline__ int gidx(int q, int row, int col) {
    return q * 512 + ((row * 16 + col) ^ (((row >> 2) & 1) << 4));
}

// 256 blocks x 320 threads (4 worker waves + 1 heater wave), ~140KB LDS ->
// 1 block/CU, all resident. Workers run at s_setprio(1); heater at 0.
__global__ __launch_bounds__(320, 1)
void fused_slstm(const float* __restrict__ x,
                 const float* __restrict__ W0, const float* __restrict__ R0,
                 const float* __restrict__ b0v,
                 const float* __restrict__ W1, const float* __restrict__ R1,
                 const float* __restrict__ b1v,
                 _Float16* __restrict__ hexhi, _Float16* __restrict__ hexlo,
                 unsigned* __restrict__ flagR, unsigned* __restrict__ flagX,
                 unsigned* __restrict__ xccbuf, unsigned* __restrict__ mech,
                 unsigned* __restrict__ probe,
                 _Float16* __restrict__ h1hi, _Float16* __restrict__ h1lo,
                 float* __restrict__ hlast, int useH1Lo)
{
    constexpr int LDSH = 4 * 16 * 64 * 8;   // 32768 f16 = 64 KB per plane
    __shared__ _Float16 lds[2 * LDSH];
    __shared__ float gbuf[4 * 512];
    __shared__ int verdLds, mechLds, fastLds;
    __shared__ int epB, epC;                // heater handshake epochs

    const int tid  = threadIdx.x;
    const int lane = tid & 63;
    const int wid  = tid >> 6;              // 0..3 workers, 4 heater
    const bool wk  = (wid < NWK_);
    const int l15  = lane & 15;
    const int l4   = lane >> 4;
    const int kg8  = l4 * 8;
    const int c    = blockIdx.x & 7;
    const int p    = blockIdx.x >> 3;
    const bool isL2 = (c >= 4);
    const int g    = c & 3;
    const int b0g  = g * MB_;

    const float* Rg  = isL2 ? R1 : R0;
    const float* bgp = isL2 ? b1v : b0v;

    if (tid == 0) { epB = 0; epC = 0; }

    // ---- stage weights: worker wave wid stages gate q=wid (frag-major f16) ----
    if (wk) {
        const int q = wid;
        const int grow = q * H_ + p * HC_ + l15;
        const float* rsrc = Rg + (size_t)grow * H_ + kg8;
        for (int kt = 0; kt < 16; ++kt) {
            const float* s = rsrc + kt * 32;
            _Float16* dhi = &lds[((q * 16 + kt) * 64 + lane) * 8];
            _Float16* dlo = dhi + LDSH;
            if (!isL2) {
                #pragma unroll
                for (int j = 0; j < 8; ++j) {
                    float v = s[j];
                    _Float16 h = (_Float16)v;
                    dhi[j] = h;
                    dlo[j] = (_Float16)(v - (float)h);   // R0_lo
                }
            } else {
                const float* ws2 = W1 + (size_t)grow * H_ + kt * 32 + kg8;
                #pragma unroll
                for (int j = 0; j < 8; ++j) {
                    dhi[j] = (_Float16)s[j];             // R1_hi
                    dlo[j] = (_Float16)ws2[j];           // W1_hi
                }
            }
        }
    }

    // ==== Phase 1: XCC mapping verdict (clique on one XCD, neighbor differs) ====
    {
        unsigned myxcc;
        asm volatile("s_getreg_b32 %0, hwreg(20, 0, 32)" : "=s"(myxcc)); // HW_REG_XCC_ID
        if (tid == 0) ast4(xccbuf + blockIdx.x, 0x100u | (myxcc & 0xFFu));
        if (wid == 0) {
            const unsigned* xp = xccbuf + ((lane & 31) * 8 + c);
            unsigned v = 0;
            int ok = 0;
            for (int it = 0; it < SPIN_BOUND; ++it) {
                v = ald4(xp);
                if (__ballot(v >= 0x100u) == ~0ull) { ok = 1; break; }
                __builtin_amdgcn_s_sleep(2);
            }
            unsigned ref = (unsigned)__shfl((int)v, 0);
            bool alleq = ok && (__ballot((v & 0xFFu) == (ref & 0xFFu)) == ~0ull);
            unsigned o = 0;
            int ok2 = 0;
            const unsigned* op = xccbuf + (c ^ 1);      // p=0 block of neighbor clique
            for (int it = 0; it < SPIN_BOUND; ++it) {
                o = ald4(op);
                if (o >= 0x100u) { ok2 = 1; break; }
                __builtin_amdgcn_s_sleep(2);
            }
            bool cand = alleq && ok2 && ((o & 0xFFu) != (ref & 0xFFu));
            if (lane == 0) verdLds = cand ? 1 : 0;
        }
    }
    __syncthreads();
    const bool candFast = (verdLds != 0);

    // ==== Phase 2: mechanism probe — PROVE plain-store/sc1-load coherence ====
    if (candFast && p == 0 && tid == 0) {
        for (unsigned k = 1; k <= 3; ++k) {
            st4_plain(probe + c * 32, k);
            asm volatile("s_waitcnt vmcnt(0)" ::: "memory");
            for (int s = 0; s < 32; ++s) __builtin_amdgcn_s_sleep(127); // ~100us gap
        }
    }
    if (candFast && wid == 0) {
        unsigned first = 0xFFFFFFFFu;
        int got = 0;
        for (int it = 0; it < (1 << 16); ++it) {       // bounded
            unsigned v = ld4_sc1(probe + c * 32);
            if (first == 0xFFFFFFFFu) first = v;
            if (v >= 3u) { got = 1; break; }
            __builtin_amdgcn_s_sleep(2);
        }
        if (p != 0 && first >= 3u) got = 0;  // can't validate repeated-read coherence
        if (lane == 0) mechLds = got;
    }
    __syncthreads();
    const int saw = candFast ? mechLds : 0;

    // ==== Phase 3: unanimous consensus via IC gather (every block publishes) ====
    if (tid == 0) ast4(mech + blockIdx.x, 0x100u | (unsigned)(saw & 1));
    if (wid == 0) {
        const unsigned* mp = mech + ((lane & 31) * 8 + c);
        unsigned v = 0;
        int ok = 0;
        for (int it = 0; it < SPIN_BOUND; ++it) {
            v = ald4(mp);
            if (__ballot(v >= 0x100u) == ~0ull) { ok = 1; break; }
            __builtin_amdgcn_s_sleep(2);
        }
        bool allsaw = ok && (__ballot((v & 1u) != 0u) == ~0ull);
        if (lane == 0) fastLds = (candFast && allsaw) ? 1 : 0;
    }

    // ---- per-thread elementwise constants (workers only) ----
    const int colIdx = tid & 15;
    const int col    = p * HC_ + colIdx;
    const int row0   = (tid >> 4) & 15;     // 0..15 for workers
    float bb[4], w0r[4][3];
    if (wk) {
        #pragma unroll
        for (int q = 0; q < 4; ++q) bb[q] = bgp[q * H_ + col];
        if (!isL2) {
            #pragma unroll
            for (int q = 0; q < 4; ++q)
                #pragma unroll
                for (int d = 0; d < 3; ++d)
                    w0r[q][d] = W0[(size_t)(q * H_ + col) * 3 + d];
        }
    }

    float cS[2] = {0.f, 0.f}, nS[2] = {0.f, 0.f}, mS[2] = {0.f, 0.f};
    const int kt0 = wid * 4;
    int dead = 0;

    __syncthreads();    // weights staged + verdict + epochs init
    const bool fast = (fastLds != 0);
    if (wk) __builtin_amdgcn_s_setprio(1);   // workers outrank the heater

    for (int t = 0; t < T_; ++t) {
        f32x4 acc[2][4];

        if (wk) {
            // ---- phase A: init own gate-grid slots = bias (+ x.W0 for L1) ----
            if (!isL2) {
                float xa[2][3];
                #pragma unroll
                for (int h = 0; h < 2; ++h) {
                    const float* xp = x + ((size_t)(b0g + row0 + h * 16) * T_ + t) * 3;
                    xa[h][0] = xp[0]; xa[h][1] = xp[1]; xa[h][2] = xp[2];
                }
                #pragma unroll
                for (int q = 0; q < 4; ++q) {
                    gbuf[gidx(q, row0, colIdx)] =
                        bb[q] + w0r[q][0]*xa[0][0] + w0r[q][1]*xa[0][1] + w0r[q][2]*xa[0][2];
                    gbuf[gidx(q, row0 + 16, colIdx)] =
                        bb[q] + w0r[q][0]*xa[1][0] + w0r[q][1]*xa[1][1] + w0r[q][2]*xa[1][2];
                }
            } else {
                #pragma unroll
                for (int q = 0; q < 4; ++q) {
                    gbuf[gidx(q, row0, colIdx)] = bb[q];
                    gbuf[gidx(q, row0 + 16, colIdx)] = bb[q];
                }
            }

            #pragma unroll
            for (int mt = 0; mt < 2; ++mt)
                #pragma unroll
                for (int q = 0; q < 4; ++q) { f32x4 z = {0.f,0.f,0.f,0.f}; acc[mt][q] = z; }

            // ---- L2 feed-forward: poll flagX, PIPELINED h1 loads + W1 MFMAs ----
            if (isL2) {
                if (!dead) {
                    const unsigned* fx = flagX + ((size_t)(g * 32 + (lane & 31)) << 5);
                    int it = 0;
                    for (;;) {
                        unsigned v = ald4(fx);
                        if (__ballot(v >= (unsigned)(t + 1)) == ~0ull) break;
                        if (++it > SPIN_BOUND) { dead = 1; break; }
                        heat(v);
                    }
                }
                asm volatile("" ::: "memory");
                f16x8 xh[4][2], xhB[4][2];
                const size_t xb0 = ((size_t)(b0g + l15) * T_ + t) * H_ + kt0 * 32 + kg8;
                const size_t xb1 = ((size_t)(b0g + 16 + l15) * T_ + t) * H_ + kt0 * 32 + kg8;
                const _Float16* q0 = h1hi + xb0;
                const _Float16* q1 = h1hi + xb1;
                if (useH1Lo) {
                    const _Float16* q2 = h1lo + xb0;
                    const _Float16* q3 = h1lo + xb1;
                    LD16("sc0 sc1", xh, xhB, q0, q1, q2, q3);
                } else {
                    asm volatile(
                        "global_load_dwordx4 %0, %8, off sc0 sc1\n\t"
                        "global_load_dwordx4 %1, %8, off offset:64 sc0 sc1\n\t"
                        "global_load_dwordx4 %2, %8, off offset:128 sc0 sc1\n\t"
                        "global_load_dwordx4 %3, %8, off offset:192 sc0 sc1\n\t"
                        "global_load_dwordx4 %4, %9, off sc0 sc1\n\t"
                        "global_load_dwordx4 %5, %9, off offset:64 sc0 sc1\n\t"
                        "global_load_dwordx4 %6, %9, off offset:128 sc0 sc1\n\t"
                        "global_load_dwordx4 %7, %9, off offset:192 sc0 sc1\n\t"
                        "s_waitcnt vmcnt(0)"
                        : "=&v"(xh[0][0]), "=&v"(xh[1][0]), "=&v"(xh[2][0]), "=&v"(xh[3][0]),
                          "=&v"(xh[0][1]), "=&v"(xh[1][1]), "=&v"(xh[2][1]), "=&v"(xh[3][1])
                        : "v"(q0), "v"(q1)
                        : "memory");
                }
                #pragma unroll
                for (int k = 0; k < 4; ++k)
                    #pragma unroll
                    for (int q = 0; q < 4; ++q) {
                        f16x8 w = *(const f16x8*)&lds[LDSH + ((q * 16 + kt0 + k) * 64 + lane) * 8];
                        acc[0][q] = MFMA(xh[k][0], w, acc[0][q]);
                        acc[1][q] = MFMA(xh[k][1], w, acc[1][q]);
                        if (useH1Lo) {
                            acc[0][q] = MFMA(xhB[k][0], w, acc[0][q]);
                            acc[1][q] = MFMA(xhB[k][1], w, acc[1][q]);
                        }
                    }
            }

            // ---- recurrent wait: every worker wave polls (bounded) ----
            if (t > 0 && !dead) {
                const unsigned* fr = flagR + ((size_t)(c * 32 + (lane & 31)) << 5);
                int it = 0;
                if (fast) {
                    for (;;) {
                        unsigned v = ld4_sc1(fr);
                        if (__ballot(v >= (unsigned)t) == ~0ull) break;
                        if (++it > SPIN_BOUND) { dead = 1; break; }
                        heat(v);
                    }
                } else {
                    for (;;) {
                        unsigned v = ald4(fr);
                        if (__ballot(v >= (unsigned)t) == ~0ull) break;
                        if (++it > SPIN_BOUND) { dead = 1; break; }
                        heat(v);
                    }
                }
                asm volatile("" ::: "memory");
            }

            // ---- recurrent A-frags: PIPELINED (sc1 fast / sc0sc1 slow) ----
            f16x8 ah[4][2], ahB[4][2];
            {
                const size_t hb = (((size_t)(t & 1) * NC_ + c) * MB_ + l15) * H_ + kt0 * 32 + kg8;
                const _Float16* ph0 = hexhi + hb;
                const _Float16* ph1 = hexhi + hb + (size_t)16 * H_;
                const _Float16* pl0 = hexlo + hb;
                const _Float16* pl1 = hexlo + hb + (size_t)16 * H_;
                if (fast) {
                    LD16("sc1", ah, ahB, ph0, ph1, pl0, pl1);
                } else {
                    LD16("sc0 sc1", ah, ahB, ph0, ph1, pl0, pl1);
                }
            }

            // ---- recurrent MFMAs ----
            #pragma unroll
            for (int k = 0; k < 4; ++k)
                #pragma unroll
                for (int q = 0; q < 4; ++q) {
                    f16x8 rh = *(const f16x8*)&lds[((q * 16 + kt0 + k) * 64 + lane) * 8];
                    acc[0][q] = MFMA(ah[k][0], rh, acc[0][q]);
                    acc[1][q] = MFMA(ah[k][1], rh, acc[1][q]);
                    acc[0][q] = MFMA(ahB[k][0], rh, acc[0][q]);
                    acc[1][q] = MFMA(ahB[k][1], rh, acc[1][q]);
                    if (!isL2) {
                        f16x8 rlo = *(const f16x8*)&lds[LDSH + ((q * 16 + kt0 + k) * 64 + lane) * 8];
                        acc[0][q] = MFMA(ah[k][0], rlo, acc[0][q]);
                        acc[1][q] = MFMA(ah[k][1], rlo, acc[1][q]);
                    }
                }

            if (wid == 0 && lane == 0) *(volatile int*)&epB = t + 1;  // heater: step waits done
        } else {
            heater_spin((volatile int*)&epB, t + 1);   // burn during phaseA+polls+loads+MFMA
        }

        __syncthreads();   // B1: phase-A writes + all worker MFMAs done
        if (wk) {
            #pragma unroll
            for (int mt = 0; mt < 2; ++mt)
                #pragma unroll
                for (int q = 0; q < 4; ++q)
                    #pragma unroll
                    for (int r = 0; r < 4; ++r)
                        atomicAdd(&gbuf[gidx(q, mt * 16 + l4 * 4 + r, l15)], acc[mt][q][r]);
        }
        __syncthreads();   // B2: all partials summed

        float hvv[2];
        unsigned pvhi[2], pvlo[2];
        if (wk) {
            // ---- elementwise sLSTM state update: 2 elements per thread ----
            #pragma unroll
            for (int h = 0; h < 2; ++h) {
                const int row = row0 + h * 16;
                float iv = gbuf[gidx(0, row, colIdx)], fv = gbuf[gidx(1, row, colIdx)];
                float zv = gbuf[gidx(2, row, colIdx)], ov = gbuf[gidx(3, row, colIdx)];
                float fm = fv + mS[h];
                float mn = fmaxf(fm, iv);
                float ig = __expf(iv - mn);
                float fg = __expf(fm - mn);
                float zc = fminf(fmaxf(zv, -15.f), 15.f);
                float e2 = __expf(2.f * zc);
                float th = (e2 - 1.f) / (e2 + 1.f);
                cS[h] = fg * cS[h] + ig * th;
                nS[h] = fg * nS[h] + ig;
                mS[h] = mn;
                float sg = 1.f / (1.f + __expf(-ov));
                float hv = sg * cS[h] / fmaxf(nS[h], 1e-6f);
                hvv[h] = hv;

                _Float16 hi = (_Float16)hv;
                _Float16 lo = (_Float16)(hv - (float)hi);
                unsigned self = (unsigned)f16bits(hi) | ((unsigned)f16bits(lo) << 16);
                unsigned part = (unsigned)__shfl_xor((int)self, 1);
                pvhi[h] = (self & 0xffffu) | ((part & 0xffffu) << 16);
                pvlo[h] = (self >> 16) | (part & 0xffff0000u);
            }

            // ---- stage 1: hex stores -> per-wave drain ----
            if (!(colIdx & 1)) {
                #pragma unroll
                for (int h = 0; h < 2; ++h) {
                    const int row = row0 + h * 16;
                    const size_t wb = (((size_t)((t + 1) & 1) * NC_ + c) * MB_ + row) * H_
                                    + p * HC_ + colIdx;
                    if (fast) {
                        *(unsigned*)(hexhi + wb) = pvhi[h];
                        *(unsigned*)(hexlo + wb) = pvlo[h];
                    } else {
                        ast4(hexhi + wb, pvhi[h]);
                        ast4(hexlo + wb, pvlo[h]);
                    }
                }
            }
            asm volatile("s_waitcnt vmcnt(0)" ::: "memory");
            if (wid == 0 && lane == 0) *(volatile int*)&epC = t + 1;  // drain done
        } else {
            heater_spin((volatile int*)&epC, t + 1);   // burn during state+stores+drain
        }
        __syncthreads();   // B3: all worker stores drained
        if (tid == 0) {
            unsigned nv = (unsigned)(t + 1);
            unsigned* frp = flagR + ((size_t)(c * 32 + p) << 5);
            if (fast) st4_plain(frp, nv);
            else      ast4(frp, nv);
            if (!isL2) ast4(flagX + ((size_t)(c * 32 + p) << 5), (unsigned)t);
        }

        // ---- h1 publish: fire-and-forget; drained by NEXT step's stage-1 drain ----
        if (wk && !isL2 && !(colIdx & 1)) {
            #pragma unroll
            for (int h = 0; h < 2; ++h) {
                const int row = row0 + h * 16;
                const size_t ob = ((size_t)(b0g + row) * T_ + t) * H_ + p * HC_ + colIdx;
                ast4(h1hi + ob, pvhi[h]);
                if (useH1Lo) ast4(h1lo + ob, pvlo[h]);
            }
        }

        if (wk && isL2 && t == T_ - 1) {
            #pragma unroll
            for (int h = 0; h < 2; ++h)
                hlast[(size_t)(b0g + row0 + h * 16) * H_ + col] = hvv[h];
        }
    }

    // ---- post-loop: L1 publishes final flagX (covers h1[T-1]) ----
    if (!isL2) {
        asm volatile("s_waitcnt vmcnt(0)" ::: "memory");
        __syncthreads();
        if (tid == 0) ast4(flagX + ((size_t)(c * 32 + p) << 5), (unsigned)(T_ + 1));
    }
}

#define OUT_ 26
__global__ __launch_bounds__(64)
void fc_kernel(const float* __restrict__ hlast, const float* __restrict__ fcw,
               const float* __restrict__ fcb, float* __restrict__ out)
{
    int b = blockIdx.x, o = threadIdx.x;
    if (o < OUT_) {
        const float4* hv = reinterpret_cast<const float4*>(hlast + (size_t)b * H_);
        const float4* wv = reinterpret_cast<const float4*>(fcw + (size_t)o * H_);
        float s = fcb[o];
        #pragma unroll 4
        for (int k = 0; k < H_ / 4; ++k) {
            float4 h4 = hv[k], w4 = wv[k];
            s += h4.x * w4.x + h4.y * w4.y + h4.z * w4.z + h4.w * w4.w;
        }
        out[(size_t)b * OUT_ + o] = s;
    }
}

extern "C" void kernel_launch(void* const* d_in, const int* in_sizes, int n_in,
                              void* d_out, int out_size, void* d_ws, size_t ws_size,
                              hipStream_t stream) {
    const float* x   = (const float*)d_in[0];
    const float* W0  = (const float*)d_in[1];
    const float* R0  = (const float*)d_in[2];
    const float* b0  = (const float*)d_in[3];
    const float* W1  = (const float*)d_in[4];
    const float* R1  = (const float*)d_in[5];
    const float* b1  = (const float*)d_in[6];
    const float* fcw = (const float*)d_in[7];
    const float* fcb = (const float*)d_in[8];
    float* out = (float*)d_out;

    if (ws_size < WS_NEED_SMALL) return;  // fail-visible rather than corrupt
    const int useH1Lo = (ws_size >= WS_NEED_FULL) ? 1 : 0;

    char* ws = (char*)d_ws;
    _Float16* hexhi = (_Float16*)(ws + WS_HEXHI);
    _Float16* hexlo = (_Float16*)(ws + WS_HEXLO);
    unsigned* flagR = (unsigned*)(ws + WS_FLAGR);
    unsigned* flagX = (unsigned*)(ws + WS_FLAGX);
    unsigned* xccb  = (unsigned*)(ws + WS_XCC);
    unsigned* mech  = (unsigned*)(ws + WS_MECH);
    unsigned* probe = (unsigned*)(ws + WS_PROBE);
    float*    hlast = (float*)(ws + WS_HLAST);
    _Float16* h1hi  = (_Float16*)(ws + WS_H1HI);
    _Float16* h1lo  = (_Float16*)(ws + WS_H1LO);

    hipMemsetAsync(ws, 0, WS_ZEROL, stream);   // h_0, flags, xcc, mech, probe
    fused_slstm<<<NC_ * P_, 320, 0, stream>>>(x, W0, R0, b0, W1, R1, b1,
                                              hexhi, hexlo, flagR, flagX,
                                              xccb, mech, probe,
                                              h1hi, h1lo, hlast, useH1Lo);
    fc_kernel<<<B_, 64, 0, stream>>>(hlast, fcw, fcb, out);
}

// Round 15
// 14847.911 us; speedup vs baseline: 1.1255x; 1.1255x over previous
//
#include <hip/hip_runtime.h>
#include <hip/hip_bf16.h>

typedef _Float16 f16x8 __attribute__((ext_vector_type(8)));
typedef float f32x4 __attribute__((ext_vector_type(4)));
typedef unsigned long long u64;

#define B_   128
#define T_   1024
#define H_   512
#define P_   32      // blocks per clique (16 h-cols each)
#define HC_  16
#define MB_  32      // batch rows per clique
#define NC_  8       // cliques: 0-3 layer1, 4-7 layer2
#define NW_  4       // waves per block (K-split)
#define SPIN_BOUND (1 << 20)

// Fragment-order layouts (the round-15 change): element index
//   hexF:  (((par*NC+c)*2+mt)*16 + kt)*512 + lane*8 + j      [512 = 64 lanes x 8]
//   h1F:   ((((size_t)t*4+g)*2+mt)*16 + kt)*512 + lane*8 + j
// Consumer reads are LANE-CONSECUTIVE (coalesced, 8 trans/instr vs 64 scattered).
#define FRAG_MT 8192        // elements per (par,c,mt) / (t,g,mt) sub-array

// ws layout (bytes)
#define WS_HEXHI  0ull            // f16 fragF [2][NC][2][16][64][8] = 524288
#define WS_HEXLO  524288ull
#define WS_FLAGR  1048576ull      // u32 [NC][32][32] 128B-padded = 32768
#define WS_FLAGX  1081344ull      // u32 [4][32][32] = 16384
#define WS_XCC    1097728ull      // u32[256]
#define WS_MECH   1098752ull
#define WS_PROBE  1099776ull
#define WS_ZEROL  1100800ull
#define WS_XT     1100800ull      // f32 xT[T][B][3] = 1572864
#define WS_HLAST  2673664ull      // f32 [B][H] = 262144
#define WS_H1HI   2935808ull      // f16 h1F hi = 134217728
#define WS_H1LO   137153536ull
#define WS_NEED_SMALL 137153536ull
#define WS_NEED_FULL  271371264ull

#define MFMA(a, b, c) __builtin_amdgcn_mfma_f32_16x16x32_f16((a), (b), (c), 0, 0, 0)

// 16 coalesced dwordx4 loads: 4 bases x 4 kt-chunks (+0/1024/2048/3072 B),
// ONE vmcnt(0). Lane offset folded into the base (lane*16B).
#define LD16C(FLAGS, D, DB, P0, P1, P2, P3)                                     \
    asm volatile(                                                               \
        "global_load_dwordx4 %0, %16, off " FLAGS "\n\t"                        \
        "global_load_dwordx4 %1, %16, off offset:1024 " FLAGS "\n\t"            \
        "global_load_dwordx4 %2, %16, off offset:2048 " FLAGS "\n\t"            \
        "global_load_dwordx4 %3, %16, off offset:3072 " FLAGS "\n\t"            \
        "global_load_dwordx4 %4, %17, off " FLAGS "\n\t"                        \
        "global_load_dwordx4 %5, %17, off offset:1024 " FLAGS "\n\t"            \
        "global_load_dwordx4 %6, %17, off offset:2048 " FLAGS "\n\t"            \
        "global_load_dwordx4 %7, %17, off offset:3072 " FLAGS "\n\t"            \
        "global_load_dwordx4 %8, %18, off " FLAGS "\n\t"                        \
        "global_load_dwordx4 %9, %18, off offset:1024 " FLAGS "\n\t"            \
        "global_load_dwordx4 %10, %18, off offset:2048 " FLAGS "\n\t"           \
        "global_load_dwordx4 %11, %18, off offset:3072 " FLAGS "\n\t"           \
        "global_load_dwordx4 %12, %19, off " FLAGS "\n\t"                       \
        "global_load_dwordx4 %13, %19, off offset:1024 " FLAGS "\n\t"           \
        "global_load_dwordx4 %14, %19, off offset:2048 " FLAGS "\n\t"           \
        "global_load_dwordx4 %15, %19, off offset:3072 " FLAGS "\n\t"           \
        "s_waitcnt vmcnt(0)"                                                    \
        : "=&v"(D[0][0]), "=&v"(D[1][0]), "=&v"(D[2][0]), "=&v"(D[3][0]),       \
          "=&v"(D[0][1]), "=&v"(D[1][1]), "=&v"(D[2][1]), "=&v"(D[3][1]),       \
          "=&v"(DB[0][0]), "=&v"(DB[1][0]), "=&v"(DB[2][0]), "=&v"(DB[3][0]),   \
          "=&v"(DB[0][1]), "=&v"(DB[1][1]), "=&v"(DB[2][1]), "=&v"(DB[3][1])    \
        : "v"(P0), "v"(P1), "v"(P2), "v"(P3)                                    \
        : "memory")

__device__ __forceinline__ unsigned ald4(const unsigned* p) {
    return __hip_atomic_load(p, __ATOMIC_RELAXED, __HIP_MEMORY_SCOPE_AGENT);
}
__device__ __forceinline__ void ast4(void* p, unsigned v) {
    __hip_atomic_store((unsigned*)p, v, __ATOMIC_RELAXED, __HIP_MEMORY_SCOPE_AGENT);
}
__device__ __forceinline__ void st4_plain(unsigned* p, unsigned v) {
    asm volatile("global_store_dword %0, %1, off" :: "v"(p), "v"(v) : "memory");
}
__device__ __forceinline__ unsigned ld4_sc1(const unsigned* p) {
    unsigned r;
    asm volatile("global_load_dword %0, %1, off sc1\n\ts_waitcnt vmcnt(0)"
                 : "=v"(r) : "v"(p) : "memory");
    return r;
}
__device__ __forceinline__ unsigned short f16bits(_Float16 h) {
    union { _Float16 f; unsigned short s; } u; u.f = h; return u.s;
}
__device__ __forceinline__ void heat(unsigned v) {
    float a = (float)(v & 7u) + 1.0f;
    #pragma unroll
    for (int i = 0; i < 16; ++i)
        asm volatile("v_fmac_f32 %0, %1, %2" : "+v"(a) : "v"(1.000001f), "v"(a));
    asm volatile("" :: "v"(a));
}
__device__ __forceinline__ int gidx(int q, int row, int col) {
    return q * 512 + ((row * 16 + col) ^ (((row >> 2) & 1) << 4));
}

// x transpose: [B][T][3] -> [T][B][3] (one-time, makes L1 phase-A coalesced)
__global__ __launch_bounds__(256)
void xt_kernel(const float* __restrict__ x, float* __restrict__ xT) {
    int idx = blockIdx.x * 256 + threadIdx.x;          // over B*T*3
    if (idx < B_ * T_ * 3) {
        int d = idx % 3, rest = idx / 3;
        int t = rest % T_, b = rest / T_;
        xT[((size_t)t * B_ + b) * 3 + d] = x[idx];
    }
}

// 256 blocks x 256 threads (4 waves), 136KB LDS -> 1 block/CU, all resident.
__global__ __launch_bounds__(256, 1)
void fused_slstm(const float* __restrict__ xT,
                 const float* __restrict__ W0, const float* __restrict__ R0,
                 const float* __restrict__ b0v,
                 const float* __restrict__ W1, const float* __restrict__ R1,
                 const float* __restrict__ b1v,
                 _Float16* __restrict__ hexFhi, _Float16* __restrict__ hexFlo,
                 unsigned* __restrict__ flagR, unsigned* __restrict__ flagX,
                 unsigned* __restrict__ xccbuf, unsigned* __restrict__ mech,
                 unsigned* __restrict__ probe,
                 _Float16* __restrict__ h1Fhi, _Float16* __restrict__ h1Flo,
                 float* __restrict__ hlast, int useH1Lo)
{
    constexpr int LDSH = 4 * 16 * 64 * 8;   // 32768 f16 = 64 KB per plane
    __shared__ _Float16 lds[2 * LDSH];
    __shared__ float gbuf[4 * 512];
    __shared__ int verdLds, mechLds, fastLds;

    const int tid  = threadIdx.x;
    const int lane = tid & 63;
    const int wid  = tid >> 6;
    const int l15  = lane & 15;
    const int l4   = lane >> 4;
    const int kg8  = l4 * 8;
    const int c    = blockIdx.x & 7;
    const int p    = blockIdx.x >> 3;
    const bool isL2 = (c >= 4);
    const int g    = c & 3;
    const int b0g  = g * MB_;

    const float* Rg  = isL2 ? R1 : R0;
    const float* bgp = isL2 ? b1v : b0v;

    // ---- stage weights: wave wid stages gate q=wid (frag-major f16) ----
    {
        const int q = wid;
        const int grow = q * H_ + p * HC_ + l15;
        const float* rsrc = Rg + (size_t)grow * H_ + kg8;
        for (int kt = 0; kt < 16; ++kt) {
            const float* s = rsrc + kt * 32;
            _Float16* dhi = &lds[((q * 16 + kt) * 64 + lane) * 8];
            _Float16* dlo = dhi + LDSH;
            if (!isL2) {
                #pragma unroll
                for (int j = 0; j < 8; ++j) {
                    float v = s[j];
                    _Float16 h = (_Float16)v;
                    dhi[j] = h;
                    dlo[j] = (_Float16)(v - (float)h);   // R0_lo
                }
            } else {
                const float* ws2 = W1 + (size_t)grow * H_ + kt * 32 + kg8;
                #pragma unroll
                for (int j = 0; j < 8; ++j) {
                    dhi[j] = (_Float16)s[j];             // R1_hi
                    dlo[j] = (_Float16)ws2[j];           // W1_hi
                }
            }
        }
    }

    // ==== Phase 1: XCC mapping verdict ====
    {
        unsigned myxcc;
        asm volatile("s_getreg_b32 %0, hwreg(20, 0, 32)" : "=s"(myxcc)); // HW_REG_XCC_ID
        if (tid == 0) ast4(xccbuf + blockIdx.x, 0x100u | (myxcc & 0xFFu));
        if (wid == 0) {
            const unsigned* xp = xccbuf + ((lane & 31) * 8 + c);
            unsigned v = 0;
            int ok = 0;
            for (int it = 0; it < SPIN_BOUND; ++it) {
                v = ald4(xp);
                if (__ballot(v >= 0x100u) == ~0ull) { ok = 1; break; }
                __builtin_amdgcn_s_sleep(2);
            }
            unsigned ref = (unsigned)__shfl((int)v, 0);
            bool alleq = ok && (__ballot((v & 0xFFu) == (ref & 0xFFu)) == ~0ull);
            unsigned o = 0;
            int ok2 = 0;
            const unsigned* op = xccbuf + (c ^ 1);
            for (int it = 0; it < SPIN_BOUND; ++it) {
                o = ald4(op);
                if (o >= 0x100u) { ok2 = 1; break; }
                __builtin_amdgcn_s_sleep(2);
            }
            bool cand = alleq && ok2 && ((o & 0xFFu) != (ref & 0xFFu));
            if (lane == 0) verdLds = cand ? 1 : 0;
        }
    }
    __syncthreads();
    const bool candFast = (verdLds != 0);

    // ==== Phase 2: mechanism probe (plain-store/sc1-load coherence) ====
    if (candFast && p == 0 && tid == 0) {
        for (unsigned k = 1; k <= 3; ++k) {
            st4_plain(probe + c * 32, k);
            asm volatile("s_waitcnt vmcnt(0)" ::: "memory");
            for (int s = 0; s < 32; ++s) __builtin_amdgcn_s_sleep(127);
        }
    }
    if (candFast && wid == 0) {
        unsigned first = 0xFFFFFFFFu;
        int got = 0;
        for (int it = 0; it < (1 << 16); ++it) {
            unsigned v = ld4_sc1(probe + c * 32);
            if (first == 0xFFFFFFFFu) first = v;
            if (v >= 3u) { got = 1; break; }
            __builtin_amdgcn_s_sleep(2);
        }
        if (p != 0 && first >= 3u) got = 0;
        if (lane == 0) mechLds = got;
    }
    __syncthreads();
    const int saw = candFast ? mechLds : 0;

    // ==== Phase 3: unanimous consensus via IC gather ====
    if (tid == 0) ast4(mech + blockIdx.x, 0x100u | (unsigned)(saw & 1));
    if (wid == 0) {
        const unsigned* mp = mech + ((lane & 31) * 8 + c);
        unsigned v = 0;
        int ok = 0;
        for (int it = 0; it < SPIN_BOUND; ++it) {
            v = ald4(mp);
            if (__ballot(v >= 0x100u) == ~0ull) { ok = 1; break; }
            __builtin_amdgcn_s_sleep(2);
        }
        bool allsaw = ok && (__ballot((v & 1u) != 0u) == ~0ull);
        if (lane == 0) fastLds = (candFast && allsaw) ? 1 : 0;
    }

    // ---- per-thread elementwise constants ----
    const int colIdx = tid & 15;
    const int col    = p * HC_ + colIdx;
    const int row0   = tid >> 4;            // 0..15
    // frag-store coords for this thread's (row, col) values:
    const int fkt  = col >> 5;              // kt chunk
    const int fl4  = (col >> 3) & 3;        // k-octet
    const int fj   = col & 7;               // element in octet (even for even colIdx)
    float bb[4], w0r[4][3];
    #pragma unroll
    for (int q = 0; q < 4; ++q) bb[q] = bgp[q * H_ + col];
    if (!isL2) {
        #pragma unroll
        for (int q = 0; q < 4; ++q)
            #pragma unroll
            for (int d = 0; d < 3; ++d)
                w0r[q][d] = W0[(size_t)(q * H_ + col) * 3 + d];
    }

    float cS[2] = {0.f, 0.f}, nS[2] = {0.f, 0.f}, mS[2] = {0.f, 0.f};
    const int kt0 = wid * 4;
    int dead = 0;

    __syncthreads();
    const bool fast = (fastLds != 0);

    for (int t = 0; t < T_; ++t) {
        // ---- phase A: init gate-grid = bias (+ xT.W0 for L1, coalesced reads) ----
        if (!isL2) {
            float xa[2][3];
            #pragma unroll
            for (int h = 0; h < 2; ++h) {
                const float* xp = xT + ((size_t)t * B_ + b0g + row0 + h * 16) * 3;
                xa[h][0] = xp[0]; xa[h][1] = xp[1]; xa[h][2] = xp[2];
            }
            #pragma unroll
            for (int q = 0; q < 4; ++q) {
                gbuf[gidx(q, row0, colIdx)] =
                    bb[q] + w0r[q][0]*xa[0][0] + w0r[q][1]*xa[0][1] + w0r[q][2]*xa[0][2];
                gbuf[gidx(q, row0 + 16, colIdx)] =
                    bb[q] + w0r[q][0]*xa[1][0] + w0r[q][1]*xa[1][1] + w0r[q][2]*xa[1][2];
            }
        } else {
            #pragma unroll
            for (int q = 0; q < 4; ++q) {
                gbuf[gidx(q, row0, colIdx)] = bb[q];
                gbuf[gidx(q, row0 + 16, colIdx)] = bb[q];
            }
        }

        f32x4 acc[2][4];
        #pragma unroll
        for (int mt = 0; mt < 2; ++mt)
            #pragma unroll
            for (int q = 0; q < 4; ++q) { f32x4 z = {0.f,0.f,0.f,0.f}; acc[mt][q] = z; }

        // ---- L2 feed-forward: poll flagX, COALESCED h1F loads + W1 MFMAs ----
        if (isL2) {
            if (!dead) {
                const unsigned* fx = flagX + ((size_t)(g * 32 + (lane & 31)) << 5);
                int it = 0;
                for (;;) {
                    unsigned v = ald4(fx);
                    if (__ballot(v >= (unsigned)(t + 1)) == ~0ull) break;
                    if (++it > SPIN_BOUND) { dead = 1; break; }
                    heat(v);
                }
            }
            asm volatile("" ::: "memory");
            f16x8 xh[4][2], xhB[4][2];
            const size_t tb = (((size_t)t * 4 + g) * 2) * FRAG_MT + kt0 * 512 + lane * 8;
            const _Float16* q0 = h1Fhi + tb;              // mt0
            const _Float16* q1 = h1Fhi + tb + FRAG_MT;    // mt1
            if (useH1Lo) {
                const _Float16* q2 = h1Flo + tb;
                const _Float16* q3 = h1Flo + tb + FRAG_MT;
                LD16C("sc0 sc1", xh, xhB, q0, q1, q2, q3);
            } else {
                asm volatile(
                    "global_load_dwordx4 %0, %8, off sc0 sc1\n\t"
                    "global_load_dwordx4 %1, %8, off offset:1024 sc0 sc1\n\t"
                    "global_load_dwordx4 %2, %8, off offset:2048 sc0 sc1\n\t"
                    "global_load_dwordx4 %3, %8, off offset:3072 sc0 sc1\n\t"
                    "global_load_dwordx4 %4, %9, off sc0 sc1\n\t"
                    "global_load_dwordx4 %5, %9, off offset:1024 sc0 sc1\n\t"
                    "global_load_dwordx4 %6, %9, off offset:2048 sc0 sc1\n\t"
                    "global_load_dwordx4 %7, %9, off offset:3072 sc0 sc1\n\t"
                    "s_waitcnt vmcnt(0)"
                    : "=&v"(xh[0][0]), "=&v"(xh[1][0]), "=&v"(xh[2][0]), "=&v"(xh[3][0]),
                      "=&v"(xh[0][1]), "=&v"(xh[1][1]), "=&v"(xh[2][1]), "=&v"(xh[3][1])
                    : "v"(q0), "v"(q1)
                    : "memory");
            }
            #pragma unroll
            for (int k = 0; k < 4; ++k)
                #pragma unroll
                for (int q = 0; q < 4; ++q) {
                    f16x8 w = *(const f16x8*)&lds[LDSH + ((q * 16 + kt0 + k) * 64 + lane) * 8];
                    acc[0][q] = MFMA(xh[k][0], w, acc[0][q]);
                    acc[1][q] = MFMA(xh[k][1], w, acc[1][q]);
                    if (useH1Lo) {
                        acc[0][q] = MFMA(xhB[k][0], w, acc[0][q]);
                        acc[1][q] = MFMA(xhB[k][1], w, acc[1][q]);
                    }
                }
        }

        // ---- recurrent wait: every wave polls (bounded) ----
        if (t > 0 && !dead) {
            const unsigned* fr = flagR + ((size_t)(c * 32 + (lane & 31)) << 5);
            int it = 0;
            if (fast) {
                for (;;) {
                    unsigned v = ld4_sc1(fr);
                    if (__ballot(v >= (unsigned)t) == ~0ull) break;
                    if (++it > SPIN_BOUND) { dead = 1; break; }
                    heat(v);
                }
            } else {
                for (;;) {
                    unsigned v = ald4(fr);
                    if (__ballot(v >= (unsigned)t) == ~0ull) break;
                    if (++it > SPIN_BOUND) { dead = 1; break; }
                    heat(v);
                }
            }
            asm volatile("" ::: "memory");
        }

        // ---- recurrent A-frags: COALESCED hexF loads ----
        f16x8 ah[4][2], ahB[4][2];
        {
            const size_t hb = (((size_t)(t & 1) * NC_ + c) * 2) * FRAG_MT + kt0 * 512 + lane * 8;
            const _Float16* ph0 = hexFhi + hb;
            const _Float16* ph1 = hexFhi + hb + FRAG_MT;
            const _Float16* pl0 = hexFlo + hb;
            const _Float16* pl1 = hexFlo + hb + FRAG_MT;
            if (fast) {
                LD16C("sc1", ah, ahB, ph0, ph1, pl0, pl1);
            } else {
                LD16C("sc0 sc1", ah, ahB, ph0, ph1, pl0, pl1);
            }
        }

        // ---- recurrent MFMAs ----
        #pragma unroll
        for (int k = 0; k < 4; ++k)
            #pragma unroll
            for (int q = 0; q < 4; ++q) {
                f16x8 rh = *(const f16x8*)&lds[((q * 16 + kt0 + k) * 64 + lane) * 8];
                acc[0][q] = MFMA(ah[k][0], rh, acc[0][q]);
                acc[1][q] = MFMA(ah[k][1], rh, acc[1][q]);
                acc[0][q] = MFMA(ahB[k][0], rh, acc[0][q]);
                acc[1][q] = MFMA(ahB[k][1], rh, acc[1][q]);
                if (!isL2) {
                    f16x8 rlo = *(const f16x8*)&lds[LDSH + ((q * 16 + kt0 + k) * 64 + lane) * 8];
                    acc[0][q] = MFMA(ah[k][0], rlo, acc[0][q]);
                    acc[1][q] = MFMA(ah[k][1], rlo, acc[1][q]);
                }
            }

        __syncthreads();
        #pragma unroll
        for (int mt = 0; mt < 2; ++mt)
            #pragma unroll
            for (int q = 0; q < 4; ++q)
                #pragma unroll
                for (int r = 0; r < 4; ++r)
                    atomicAdd(&gbuf[gidx(q, mt * 16 + l4 * 4 + r, l15)], acc[mt][q][r]);
        __syncthreads();

        // ---- elementwise sLSTM state update: 2 elements per thread ----
        float hvv[2];
        unsigned pv[2][2];                 // [h][plane] packed (col, col+1)
        #pragma unroll
        for (int h = 0; h < 2; ++h) {
            const int row = row0 + h * 16;
            float iv = gbuf[gidx(0, row, colIdx)], fv = gbuf[gidx(1, row, colIdx)];
            float zv = gbuf[gidx(2, row, colIdx)], ov = gbuf[gidx(3, row, colIdx)];
            float fm = fv + mS[h];
            float mn = fmaxf(fm, iv);
            float ig = __expf(iv - mn);
            float fg = __expf(fm - mn);
            float zc = fminf(fmaxf(zv, -15.f), 15.f);
            float e2 = __expf(2.f * zc);
            float th = (e2 - 1.f) / (e2 + 1.f);
            cS[h] = fg * cS[h] + ig * th;
            nS[h] = fg * nS[h] + ig;
            mS[h] = mn;
            float sg = 1.f / (1.f + __expf(-ov));
            float hv = sg * cS[h] / fmaxf(nS[h], 1e-6f);
            hvv[h] = hv;

            _Float16 hi = (_Float16)hv;
            _Float16 lo = (_Float16)(hv - (float)hi);
            unsigned self = (unsigned)f16bits(hi) | ((unsigned)f16bits(lo) << 16);
            unsigned part = (unsigned)__shfl_xor((int)self, 1);
            pv[h][0] = (self & 0xffffu) | ((part & 0xffffu) << 16);   // hi: col,col+1
            pv[h][1] = (self >> 16) | (part & 0xffff0000u);           // lo
        }

        // ---- stage 1: hexF stores (frag-order, packed u32) -> drain -> flagR ----
        if (!(colIdx & 1)) {
            #pragma unroll
            for (int h = 0; h < 2; ++h) {
                const size_t fe = (((size_t)((t + 1) & 1) * NC_ + c) * 2 + h) * FRAG_MT
                                + fkt * 512 + (size_t)(row0 + 16 * fl4) * 8 + fj;
                if (fast) {
                    *(unsigned*)(hexFhi + fe) = pv[h][0];
                    *(unsigned*)(hexFlo + fe) = pv[h][1];
                } else {
                    ast4(hexFhi + fe, pv[h][0]);
                    ast4(hexFlo + fe, pv[h][1]);
                }
            }
        }
        asm volatile("s_waitcnt vmcnt(0)" ::: "memory");
        __syncthreads();
        if (tid == 0) {
            unsigned nv = (unsigned)(t + 1);
            unsigned* frp = flagR + ((size_t)(c * 32 + p) << 5);
            if (fast) st4_plain(frp, nv);
            else      ast4(frp, nv);
            if (!isL2) ast4(flagX + ((size_t)(c * 32 + p) << 5), (unsigned)t);
        }

        // ---- h1F publish (L1): fire-and-forget frag-order stores;
        // drained by NEXT step's stage-1 drain before flagX passes them ----
        if (!isL2 && !(colIdx & 1)) {
            #pragma unroll
            for (int h = 0; h < 2; ++h) {
                const size_t fe = (((size_t)t * 4 + g) * 2 + h) * FRAG_MT
                                + fkt * 512 + (size_t)(row0 + 16 * fl4) * 8 + fj;
                ast4(h1Fhi + fe, pv[h][0]);
                if (useH1Lo) ast4(h1Flo + fe, pv[h][1]);
            }
        }

        if (isL2 && t == T_ - 1) {
            #pragma unroll
            for (int h = 0; h < 2; ++h)
                hlast[(size_t)(b0g + row0 + h * 16) * H_ + col] = hvv[h];
        }
    }

    // ---- post-loop: L1 publishes final flagX (covers h1F[T-1]) ----
    if (!isL2) {
        asm volatile("s_waitcnt vmcnt(0)" ::: "memory");
        __syncthreads();
        if (tid == 0) ast4(flagX + ((size_t)(c * 32 + p) << 5), (unsigned)(T_ + 1));
    }
}

#define OUT_ 26
__global__ __launch_bounds__(64)
void fc_kernel(const float* __restrict__ hlast, const float* __restrict__ fcw,
               const float* __restrict__ fcb, float* __restrict__ out)
{
    int b = blockIdx.x, o = threadIdx.x;
    if (o < OUT_) {
        const float4* hv = reinterpret_cast<const float4*>(hlast + (size_t)b * H_);
        const float4* wv = reinterpret_cast<const float4*>(fcw + (size_t)o * H_);
        float s = fcb[o];
        #pragma unroll 4
        for (int k = 0; k < H_ / 4; ++k) {
            float4 h4 = hv[k], w4 = wv[k];
            s += h4.x * w4.x + h4.y * w4.y + h4.z * w4.z + h4.w * w4.w;
        }
        out[(size_t)b * OUT_ + o] = s;
    }
}

extern "C" void kernel_launch(void* const* d_in, const int* in_sizes, int n_in,
                              void* d_out, int out_size, void* d_ws, size_t ws_size,
                              hipStream_t stream) {
    const float* x   = (const float*)d_in[0];
    const float* W0  = (const float*)d_in[1];
    const float* R0  = (const float*)d_in[2];
    const float* b0  = (const float*)d_in[3];
    const float* W1  = (const float*)d_in[4];
    const float* R1  = (const float*)d_in[5];
    const float* b1  = (const float*)d_in[6];
    const float* fcw = (const float*)d_in[7];
    const float* fcb = (const float*)d_in[8];
    float* out = (float*)d_out;

    if (ws_size < WS_NEED_SMALL) return;  // fail-visible rather than corrupt
    const int useH1Lo = (ws_size >= WS_NEED_FULL) ? 1 : 0;

    char* ws = (char*)d_ws;
    _Float16* hexFhi = (_Float16*)(ws + WS_HEXHI);
    _Float16* hexFlo = (_Float16*)(ws + WS_HEXLO);
    unsigned* flagR  = (unsigned*)(ws + WS_FLAGR);
    unsigned* flagX  = (unsigned*)(ws + WS_FLAGX);
    unsigned* xccb   = (unsigned*)(ws + WS_XCC);
    unsigned* mech   = (unsigned*)(ws + WS_MECH);
    unsigned* probe  = (unsigned*)(ws + WS_PROBE);
    float*    xTp    = (float*)(ws + WS_XT);
    float*    hlast  = (float*)(ws + WS_HLAST);
    _Float16* h1Fhi  = (_Float16*)(ws + WS_H1HI);
    _Float16* h1Flo  = (_Float16*)(ws + WS_H1LO);

    hipMemsetAsync(ws, 0, WS_ZEROL, stream);   // hexF (h_0=0), flags, xcc, mech, probe
    xt_kernel<<<(B_ * T_ * 3 + 255) / 256, 256, 0, stream>>>(x, xTp);
    fused_slstm<<<NC_ * P_, NW_ * 64, 0, stream>>>(xTp, W0, R0, b0, W1, R1, b1,
                                                   hexFhi, hexFlo, flagR, flagX,
                                                   xccb, mech, probe,
                                                   h1Fhi, h1Flo, hlast, useH1Lo);
    fc_kernel<<<B_, 64, 0, stream>>>(hlast, fcw, fcb, out);
}